// Round 1
// baseline (4491.064 us; speedup 1.0000x reference)
//
#include <hip/hip_runtime.h>
#include <hip/hip_bf16.h>
#include <hip/hip_fp16.h>

// LSTM: S=2048, B=128, I=128, H=128, 4H=512
// out = [h_seq (S*B*H) | h_T (B*H) | c_T (B*H)], fp32
// ws  = xg (S*B*512) fp16 = 268 MB

#define S_LEN 2048
#define BATCH 128
#define HID   128
#define G4    512

// ---------------------------------------------------------------------------
// Phase 1: xg[m][n] = sum_k x[m][k] * V[n][k] + b[n] + b2[n],  fp16 out
// M = 262144, N = 512, K = 128. Tile 128x128, K in 2 halves of 64.
// LDS: 2 x (128 rows x 16 float4) XOR-swizzled = 64 KB exactly.
// ---------------------------------------------------------------------------
__global__ __launch_bounds__(256, 2)
void xg_gemm(const float* __restrict__ x, const float* __restrict__ V,
             const float* __restrict__ b, const float* __restrict__ b2,
             __half* __restrict__ xg)
{
    __shared__ float4 As[128 * 16];
    __shared__ float4 Bs[128 * 16];

    const int t  = threadIdx.x;
    const int tx = t & 15;
    const int ty = t >> 4;
    const int m0 = blockIdx.y * 128;
    const int n0 = blockIdx.x * 128;

    float acc[8][8];
#pragma unroll
    for (int i = 0; i < 8; ++i)
#pragma unroll
        for (int j = 0; j < 8; ++j) acc[i][j] = 0.f;

    const float4* xf4 = (const float4*)x;   // 32 float4 per row (K=128)
    const float4* Vf4 = (const float4*)V;

    for (int kh = 0; kh < 2; ++kh) {
        // cooperative tile load: 128 rows x 16 float4, 2048 float4 / 256 thr = 8 each
#pragma unroll
        for (int r = 0; r < 8; ++r) {
            int flat = t + 256 * r;
            int row  = flat >> 4;
            int k4   = flat & 15;
            int sw   = k4 ^ (row & 15);               // XOR swizzle
            As[row * 16 + sw] = xf4[(long)(m0 + row) * 32 + kh * 16 + k4];
            Bs[row * 16 + sw] = Vf4[(n0 + row) * 32 + kh * 16 + k4];
        }
        __syncthreads();
#pragma unroll
        for (int k4 = 0; k4 < 16; ++k4) {
            float4 a4[8], b4[8];
            const int pa = k4 ^ ty;   // rows ty+16i all have (row&15)==ty
            const int pb = k4 ^ tx;   // rows tx+16j all have (row&15)==tx
#pragma unroll
            for (int i = 0; i < 8; ++i) a4[i] = As[(ty + 16 * i) * 16 + pa];
#pragma unroll
            for (int j = 0; j < 8; ++j) b4[j] = Bs[(tx + 16 * j) * 16 + pb];
#pragma unroll
            for (int i = 0; i < 8; ++i)
#pragma unroll
                for (int j = 0; j < 8; ++j) {
                    acc[i][j] += a4[i].x * b4[j].x;
                    acc[i][j] += a4[i].y * b4[j].y;
                    acc[i][j] += a4[i].z * b4[j].z;
                    acc[i][j] += a4[i].w * b4[j].w;
                }
        }
        __syncthreads();
    }

    float bias[8];
#pragma unroll
    for (int j = 0; j < 8; ++j) {
        int col = n0 + tx + 16 * j;
        bias[j] = b[col] + b2[col];
    }
#pragma unroll
    for (int i = 0; i < 8; ++i) {
        long m = (long)(m0 + ty + 16 * i);
#pragma unroll
        for (int j = 0; j < 8; ++j) {
            int col = n0 + tx + 16 * j;
            xg[m * G4 + col] = __float2half(acc[i][j] + bias[j]);
        }
    }
}

// ---------------------------------------------------------------------------
// Phase 2: sequential scan. One workgroup per batch element.
// 256 threads; thread t owns gate rows t and t+256 (W rows in 256 VGPRs).
// h broadcast from LDS (ds_read_b128, same-address = free broadcast).
// ---------------------------------------------------------------------------
__device__ __forceinline__ float fsig(float x) {
    return __builtin_amdgcn_rcpf(1.f + __expf(-x));
}
__device__ __forceinline__ float ftanh(float x) {
    // tanh(x) = 1 - 2/(1+e^{2x}); inf-graceful at both ends
    return 1.f - 2.f * __builtin_amdgcn_rcpf(1.f + __expf(2.f * x));
}

__global__ __launch_bounds__(256, 1)
void lstm_scan(const __half* __restrict__ xg, const float* __restrict__ W,
               float* __restrict__ out)
{
    const int b = blockIdx.x;
    const int t = threadIdx.x;

    __shared__ __align__(16) float h_lds[HID];
    __shared__ __align__(16) float gates[G4];

    // W rows t and t+256 into registers (fully unrolled -> stays in VGPRs)
    float4 w0[32], w1[32];
    const float4* Wf4 = (const float4*)W;
#pragma unroll
    for (int q = 0; q < 32; ++q) w0[q] = Wf4[t * 32 + q];
#pragma unroll
    for (int q = 0; q < 32; ++q) w1[q] = Wf4[(t + 256) * 32 + q];

    float c = 0.f;
    if (t < HID) h_lds[t] = 0.f;
    __syncthreads();

    const __half* xgp = xg + (long)b * G4;
    float xv0 = __half2float(xgp[t]);
    float xv1 = __half2float(xgp[t + 256]);

    float* out_h = out + (long)b * HID;
    const long SBH = (long)S_LEN * BATCH * HID;   // 33554432

    for (int s = 0; s < S_LEN; ++s) {
        // prefetch next step's xg (consumed next iteration; hides HBM latency)
        int sn = (s + 1 < S_LEN) ? s + 1 : s;
        float nx0 = __half2float(xgp[(long)sn * (BATCH * G4) + t]);
        float nx1 = __half2float(xgp[(long)sn * (BATCH * G4) + t + 256]);

        float acc0 = xv0, acc1 = xv1;
#pragma unroll
        for (int q = 0; q < 32; ++q) {
            float4 hv = *((const float4*)h_lds + q);
            acc0 += w0[q].x * hv.x; acc0 += w0[q].y * hv.y;
            acc0 += w0[q].z * hv.z; acc0 += w0[q].w * hv.w;
            acc1 += w1[q].x * hv.x; acc1 += w1[q].y * hv.y;
            acc1 += w1[q].z * hv.z; acc1 += w1[q].w * hv.w;
        }

        // rows t in [0,256): i,f -> sigmoid. rows t+256: [256,384)=g tanh, [384,512)=o sigmoid
        float act0 = fsig(acc0);
        float act1 = (t < 128) ? ftanh(acc1) : fsig(acc1);   // wave-uniform branch
        gates[t]       = act0;
        gates[t + 256] = act1;
        __syncthreads();

        if (t < HID) {
            float gi = gates[t];
            float gf = gates[t + 128];
            float gg = gates[t + 256];
            float go = gates[t + 384];
            c = gf * c + gi * gg;
            float h = go * ftanh(c);
            h_lds[t] = h;
            out_h[(long)s * (BATCH * HID) + t] = h;
        }
        __syncthreads();

        xv0 = nx0; xv1 = nx1;
    }

    if (t < HID) {
        out[SBH + (long)b * HID + t]                       = h_lds[t];  // h_T
        out[SBH + (long)BATCH * HID + (long)b * HID + t]   = c;         // c_T
    }
}

// ---------------------------------------------------------------------------
extern "C" void kernel_launch(void* const* d_in, const int* in_sizes, int n_in,
                              void* d_out, int out_size, void* d_ws, size_t ws_size,
                              hipStream_t stream) {
    const float* x  = (const float*)d_in[0];
    const float* V  = (const float*)d_in[1];
    const float* W  = (const float*)d_in[2];
    const float* b  = (const float*)d_in[3];
    const float* b2 = (const float*)d_in[4];
    float* out = (float*)d_out;
    __half* xg = (__half*)d_ws;   // needs 2048*128*512*2 = 268435456 B

    dim3 g1(G4 / 128, (S_LEN * BATCH) / 128);   // (4, 2048)
    xg_gemm<<<g1, dim3(256), 0, stream>>>(x, V, b, b2, xg);
    lstm_scan<<<dim3(BATCH), dim3(256), 0, stream>>>(xg, W, out);
}

// Round 2
// 1531.471 us; speedup vs baseline: 2.9325x; 2.9325x over previous
//
#include <hip/hip_runtime.h>
#include <hip/hip_bf16.h>
#include <hip/hip_fp16.h>

// LSTM: S=2048, B=128, I=128, H=128, 4H=512
// out = [h_seq (S*B*H) | h_T (B*H) | c_T (B*H)], fp32
// ws  = xg (S*B*512) fp16 = 268 MB

#define S_LEN 2048
#define BATCH 128
#define HID   128
#define G4    512

typedef _Float16 h2_t __attribute__((ext_vector_type(2)));
typedef _Float16 h8_t __attribute__((ext_vector_type(8)));
typedef float    f4_t __attribute__((ext_vector_type(4)));

// ---------------------------------------------------------------------------
// Phase 1: xg[m][n] = sum_k x[m][k]*V[n][k] + b[n] + b2[n], fp16 out, f16 MFMA
// M=262144, N=512, K=128. Tile 128x128, whole K in one LDS stage (64 KB).
// LDS rows of 16 chunks (8 halfs); chunk j stored at j^(row&15) (bank swizzle).
// ---------------------------------------------------------------------------
__global__ __launch_bounds__(256, 2)
void xg_gemm(const float* __restrict__ x, const float* __restrict__ V,
             const float* __restrict__ b, const float* __restrict__ b2,
             __half* __restrict__ xg)
{
    __shared__ h8_t As[128 * 16];   // 32 KB
    __shared__ h8_t Bs[128 * 16];   // 32 KB

    const int t  = threadIdx.x;
    const int m0 = blockIdx.y * 128;
    const int n0 = blockIdx.x * 128;

    // stage both tiles, fp32 -> fp16: 2048 chunks per matrix, 8 per thread
#pragma unroll
    for (int r = 0; r < 8; ++r) {
        int id  = t + 256 * r;
        int row = id >> 4;
        int j   = id & 15;
        const float4* gx = (const float4*)(x + (long)(m0 + row) * 128 + j * 8);
        float4 a0 = gx[0], a1 = gx[1];
        h8_t ha = { (_Float16)a0.x, (_Float16)a0.y, (_Float16)a0.z, (_Float16)a0.w,
                    (_Float16)a1.x, (_Float16)a1.y, (_Float16)a1.z, (_Float16)a1.w };
        As[row * 16 + (j ^ (row & 15))] = ha;
        const float4* gv = (const float4*)(V + (long)(n0 + row) * 128 + j * 8);
        float4 b0 = gv[0], b1 = gv[1];
        h8_t hb = { (_Float16)b0.x, (_Float16)b0.y, (_Float16)b0.z, (_Float16)b0.w,
                    (_Float16)b1.x, (_Float16)b1.y, (_Float16)b1.z, (_Float16)b1.w };
        Bs[row * 16 + (j ^ (row & 15))] = hb;
    }
    __syncthreads();

    const int w    = t >> 6;     // wave 0..3 -> rows [w*32, w*32+32)
    const int lane = t & 63;
    const int m    = lane & 15;  // A-frag row / B-frag col (lane&15)
    const int quad = lane >> 4;  // k = quad*8 + j

    f4_t acc[2][8];
#pragma unroll
    for (int i = 0; i < 2; ++i)
#pragma unroll
        for (int j = 0; j < 8; ++j) acc[i][j] = (f4_t)0.f;

#pragma unroll
    for (int ks = 0; ks < 4; ++ks) {          // K-steps of 32
        int ch = ks * 4 + quad;               // 8-half chunk index
        h8_t a0 = As[(w * 32      + m) * 16 + (ch ^ m)];
        h8_t a1 = As[(w * 32 + 16 + m) * 16 + (ch ^ m)];
#pragma unroll
        for (int nt = 0; nt < 8; ++nt) {
            h8_t bf = Bs[(nt * 16 + m) * 16 + (ch ^ m)];
            acc[0][nt] = __builtin_amdgcn_mfma_f32_16x16x32_f16(a0, bf, acc[0][nt], 0, 0, 0);
            acc[1][nt] = __builtin_amdgcn_mfma_f32_16x16x32_f16(a1, bf, acc[1][nt], 0, 0, 0);
        }
    }

    // epilogue: C/D layout col=lane&15, row=quad*4+reg
#pragma unroll
    for (int nt = 0; nt < 8; ++nt) {
        int col = n0 + nt * 16 + m;
        float bias = b[col] + b2[col];
#pragma unroll
        for (int mi = 0; mi < 2; ++mi) {
#pragma unroll
            for (int rg = 0; rg < 4; ++rg) {
                long mrow = (long)(m0 + w * 32 + mi * 16 + quad * 4 + rg);
                xg[mrow * G4 + col] = __float2half(acc[mi][nt][rg] + bias);
            }
        }
    }
}

// ---------------------------------------------------------------------------
// Phase 2: scan. 128 WGs (one per batch) x 512 threads (8 waves, 2/SIMD).
// Thread t: kh = t&1 (K-half), rb = t>>1; computes K-half partials of gate
// rows rb (i/f) and rb+256 (g/o) with v_dot2_f32_f16, pair-reduced via
// shfl_xor(1). Raw s_barrier (lgkmcnt only) keeps global loads/stores in
// flight across steps — no vmcnt(0) drain.
// ---------------------------------------------------------------------------
__device__ __forceinline__ float fsig(float x) {
    return __builtin_amdgcn_rcpf(1.f + __expf(-x));
}
__device__ __forceinline__ float ftanh(float x) {
    return 1.f - 2.f * __builtin_amdgcn_rcpf(1.f + __expf(2.f * x));
}
__device__ __forceinline__ void bar() {
    asm volatile("s_waitcnt lgkmcnt(0)" ::: "memory");
    __builtin_amdgcn_s_barrier();
    asm volatile("" ::: "memory");
}
__device__ __forceinline__ h2_t f2h2(float f) {
    union { float f; h2_t h; } u; u.f = f; return u.h;
}

#if __has_builtin(__builtin_amdgcn_fdot2)
#define FDOT2(a, b, c) __builtin_amdgcn_fdot2((a), (b), (c), false)
#else
__device__ __forceinline__ float FDOT2(h2_t a, h2_t b, float c) {
    return c + (float)a[0] * (float)b[0] + (float)a[1] * (float)b[1];
}
#endif

__global__ __launch_bounds__(512, 2)
void lstm_scan(const __half* __restrict__ xg, const float* __restrict__ W,
               float* __restrict__ out)
{
    const int bidx = blockIdx.x;
    const int t    = threadIdx.x;
    const int kh   = t & 1;        // which half of K this lane handles
    const int rb   = t >> 1;       // 0..255
    const int n0   = rb;           // gate row for acc0 (i if rb<128 else f)
    const int n1   = rb + 256;     // gate row for acc1 (g if rb<128 else o)

    __shared__ __align__(16) __half h_lds[HID];   // 256 B
    __shared__ float gates[G4];                   // 2 KB

    // W rows n0, n1, K-slice [kh*64, kh*64+64) -> fp16 half2 x32 each
    h2_t w0[32], w1[32];
    {
        const float4* W0 = (const float4*)(W + n0 * 128 + kh * 64);
        const float4* W1 = (const float4*)(W + n1 * 128 + kh * 64);
#pragma unroll
        for (int q = 0; q < 16; ++q) {
            float4 v = W0[q];
            w0[2 * q]     = h2_t{ (_Float16)v.x, (_Float16)v.y };
            w0[2 * q + 1] = h2_t{ (_Float16)v.z, (_Float16)v.w };
        }
#pragma unroll
        for (int q = 0; q < 16; ++q) {
            float4 v = W1[q];
            w1[2 * q]     = h2_t{ (_Float16)v.x, (_Float16)v.y };
            w1[2 * q + 1] = h2_t{ (_Float16)v.z, (_Float16)v.w };
        }
    }

    if (t < HID) h_lds[t] = __float2half(0.f);
    float c = 0.f, hlast = 0.f;
    __syncthreads();

    // this lane's xg column = the row it finalizes after the pair-reduce
    const int myrow = kh ? n1 : n0;
    const __half* xgp = xg + (long)bidx * G4 + myrow;
    const long step_stride = (long)BATCH * G4;    // 65536

    // prefetch depth 2
    float p0 = __half2float(xgp[0]);
    float p1 = __half2float(xgp[step_stride]);

    const bool use_tanh = (kh == 1) && (rb < 128);   // g-gate rows
    float* out_h = out + (long)bidx * HID;
    const long SBH = (long)S_LEN * BATCH * HID;

    for (int s = 0; s < S_LEN; ++s) {
        // prefetch s+2 (stays in flight across the raw barriers)
        long soff = (long)((s + 2 < S_LEN) ? s + 2 : S_LEN - 1) * step_stride;
        float nx = __half2float(xgp[soff]);
        float xv = p0;

        // dot over this lane's K-half of h (fp16 in LDS, 8 x b128)
        const float4* hp = (const float4*)h_lds + kh * 8;
        float acc0 = 0.f, acc1 = 0.f;
#pragma unroll
        for (int q = 0; q < 8; ++q) {
            float4 hv = hp[q];
            h2_t ha = f2h2(hv.x), hb = f2h2(hv.y), hc = f2h2(hv.z), hd = f2h2(hv.w);
            acc0 = FDOT2(w0[4 * q],     ha, acc0);
            acc0 = FDOT2(w0[4 * q + 1], hb, acc0);
            acc0 = FDOT2(w0[4 * q + 2], hc, acc0);
            acc0 = FDOT2(w0[4 * q + 3], hd, acc0);
            acc1 = FDOT2(w1[4 * q],     ha, acc1);
            acc1 = FDOT2(w1[4 * q + 1], hb, acc1);
            acc1 = FDOT2(w1[4 * q + 2], hc, acc1);
            acc1 = FDOT2(w1[4 * q + 3], hd, acc1);
        }
        // pair-reduce across the two K-halves (lanes 2k, 2k+1)
        float full0 = acc0 + __shfl_xor(acc0, 1);
        float full1 = acc1 + __shfl_xor(acc1, 1);
        float full  = (kh ? full1 : full0) + xv;

        // tanh(x) = 2*sigmoid(2x)-1 -> single exp for either activation
        float xx  = use_tanh ? 2.f * full : full;
        float sg  = fsig(xx);
        float act = use_tanh ? 2.f * sg - 1.f : sg;
        gates[myrow] = act;
        bar();

        if (t < HID) {
            float gi = gates[t];
            float gf = gates[t + 128];
            float gg = gates[t + 256];
            float go = gates[t + 384];
            c = gf * c + gi * gg;
            float h = go * ftanh(c);
            hlast = h;
            h_lds[t] = __float2half(h);
            out_h[(long)s * (BATCH * HID) + t] = h;   // in flight past barrier
        }
        bar();

        p0 = p1; p1 = nx;
    }

    if (t < HID) {
        out[SBH + (long)bidx * HID + t]                     = hlast;  // h_T
        out[SBH + (long)BATCH * HID + (long)bidx * HID + t] = c;      // c_T
    }
}

// ---------------------------------------------------------------------------
extern "C" void kernel_launch(void* const* d_in, const int* in_sizes, int n_in,
                              void* d_out, int out_size, void* d_ws, size_t ws_size,
                              hipStream_t stream) {
    const float* x  = (const float*)d_in[0];
    const float* V  = (const float*)d_in[1];
    const float* W  = (const float*)d_in[2];
    const float* b  = (const float*)d_in[3];
    const float* b2 = (const float*)d_in[4];
    float* out = (float*)d_out;
    __half* xg = (__half*)d_ws;   // 2048*128*512*2 = 268435456 B

    dim3 g1(G4 / 128, (S_LEN * BATCH) / 128);   // (4, 2048)
    xg_gemm<<<g1, dim3(256), 0, stream>>>(x, V, b, b2, xg);
    lstm_scan<<<dim3(BATCH), dim3(512), 0, stream>>>(xg, W, out);
}

// Round 3
// 1434.304 us; speedup vs baseline: 3.1312x; 1.0677x over previous
//
#include <hip/hip_runtime.h>
#include <hip/hip_bf16.h>
#include <hip/hip_fp16.h>

// LSTM: S=2048, B=128, I=128, H=128, 4H=512
// out = [h_seq (S*B*H) | h_T (B*H) | c_T (B*H)], fp32
// ws  = xg (S*B*512) fp16 = 268 MB

#define S_LEN 2048
#define BATCH 128
#define HID   128
#define G4    512

typedef _Float16 h2_t __attribute__((ext_vector_type(2)));
typedef _Float16 h8_t __attribute__((ext_vector_type(8)));
typedef float    f4_t __attribute__((ext_vector_type(4)));

// ---------------------------------------------------------------------------
// Phase 1: xg[m][n] = sum_k x[m][k]*V[n][k] + b[n] + b2[n], fp16 out, f16 MFMA
// (unchanged from round 2: ~250 us)
// ---------------------------------------------------------------------------
__global__ __launch_bounds__(256, 2)
void xg_gemm(const float* __restrict__ x, const float* __restrict__ V,
             const float* __restrict__ b, const float* __restrict__ b2,
             __half* __restrict__ xg)
{
    __shared__ h8_t As[128 * 16];   // 32 KB
    __shared__ h8_t Bs[128 * 16];   // 32 KB

    const int t  = threadIdx.x;
    const int m0 = blockIdx.y * 128;
    const int n0 = blockIdx.x * 128;

#pragma unroll
    for (int r = 0; r < 8; ++r) {
        int id  = t + 256 * r;
        int row = id >> 4;
        int j   = id & 15;
        const float4* gx = (const float4*)(x + (long)(m0 + row) * 128 + j * 8);
        float4 a0 = gx[0], a1 = gx[1];
        h8_t ha = { (_Float16)a0.x, (_Float16)a0.y, (_Float16)a0.z, (_Float16)a0.w,
                    (_Float16)a1.x, (_Float16)a1.y, (_Float16)a1.z, (_Float16)a1.w };
        As[row * 16 + (j ^ (row & 15))] = ha;
        const float4* gv = (const float4*)(V + (long)(n0 + row) * 128 + j * 8);
        float4 b0 = gv[0], b1 = gv[1];
        h8_t hb = { (_Float16)b0.x, (_Float16)b0.y, (_Float16)b0.z, (_Float16)b0.w,
                    (_Float16)b1.x, (_Float16)b1.y, (_Float16)b1.z, (_Float16)b1.w };
        Bs[row * 16 + (j ^ (row & 15))] = hb;
    }
    __syncthreads();

    const int w    = t >> 6;
    const int lane = t & 63;
    const int m    = lane & 15;
    const int quad = lane >> 4;

    f4_t acc[2][8];
#pragma unroll
    for (int i = 0; i < 2; ++i)
#pragma unroll
        for (int j = 0; j < 8; ++j) acc[i][j] = (f4_t)0.f;

#pragma unroll
    for (int ks = 0; ks < 4; ++ks) {
        int ch = ks * 4 + quad;
        h8_t a0 = As[(w * 32      + m) * 16 + (ch ^ m)];
        h8_t a1 = As[(w * 32 + 16 + m) * 16 + (ch ^ m)];
#pragma unroll
        for (int nt = 0; nt < 8; ++nt) {
            h8_t bf = Bs[(nt * 16 + m) * 16 + (ch ^ m)];
            acc[0][nt] = __builtin_amdgcn_mfma_f32_16x16x32_f16(a0, bf, acc[0][nt], 0, 0, 0);
            acc[1][nt] = __builtin_amdgcn_mfma_f32_16x16x32_f16(a1, bf, acc[1][nt], 0, 0, 0);
        }
    }

#pragma unroll
    for (int nt = 0; nt < 8; ++nt) {
        int col = n0 + nt * 16 + m;
        float bias = b[col] + b2[col];
#pragma unroll
        for (int mi = 0; mi < 2; ++mi) {
#pragma unroll
            for (int rg = 0; rg < 4; ++rg) {
                long mrow = (long)(m0 + w * 32 + mi * 16 + quad * 4 + rg);
                xg[mrow * G4 + col] = __float2half(acc[mi][nt][rg] + bias);
            }
        }
    }
}

// ---------------------------------------------------------------------------
// Phase 2: scan. 128 WGs x 512 threads. lane = (hid = t>>2, kq = t&3).
// Lane holds W rows {hid+128r} K-quarter kq in regs. Per step:
//   4x ds_read_b128 (h quarter) -> 4x16 fdot2 -> DPP quad butterfly (VALU!)
//   -> lane kq activates gate kq -> DPP quad broadcast -> c update in regs
//   -> kq==0 writes h to other LDS buffer + global. ONE lgkm-only barrier.
// ---------------------------------------------------------------------------
__device__ __forceinline__ float fsig(float x) {
    return __builtin_amdgcn_rcpf(1.f + __expf(-x));
}
__device__ __forceinline__ float ftanh(float x) {
    return 1.f - 2.f * __builtin_amdgcn_rcpf(1.f + __expf(2.f * x));
}
__device__ __forceinline__ void bar() {
    asm volatile("s_waitcnt lgkmcnt(0)" ::: "memory");
    __builtin_amdgcn_s_barrier();
    asm volatile("" ::: "memory");
}

#if __has_builtin(__builtin_amdgcn_fdot2)
#define FDOT2(a, b, c) __builtin_amdgcn_fdot2((a), (b), (c), false)
#else
__device__ __forceinline__ float FDOT2(h2_t a, h2_t b, float c) {
    return c + (float)a[0] * (float)b[0] + (float)a[1] * (float)b[1];
}
#endif

template <int CTRL>
__device__ __forceinline__ float dpp_mov_f(float x) {
#if __has_builtin(__builtin_amdgcn_mov_dpp)
    int xi = __builtin_bit_cast(int, x);
    int yi = __builtin_amdgcn_mov_dpp(xi, CTRL, 0xf, 0xf, true);
    return __builtin_bit_cast(float, yi);
#else
    // fallback: shuffle within wave (CTRL is a quad_perm with identical digits
    // or an xor pattern; handled by callers only with these two uses)
    return x; // never taken on gfx950
#endif
}
// quad_perm ctrl bytes
#define QP_XOR1  0xB1   // [1,0,3,2]
#define QP_XOR2  0x4E   // [2,3,0,1]
#define QP_BC0   0x00   // [0,0,0,0]
#define QP_BC1   0x55   // [1,1,1,1]
#define QP_BC2   0xAA   // [2,2,2,2]
#define QP_BC3   0xFF   // [3,3,3,3]

__global__ __launch_bounds__(512, 2)
void lstm_scan(const __half* __restrict__ xg, const float* __restrict__ W,
               float* __restrict__ out)
{
    const int bidx = blockIdx.x;
    const int t    = threadIdx.x;
    const int hid  = t >> 2;     // 0..127
    const int kq   = t & 3;      // K-quarter AND owned gate index

    __shared__ __align__(16) __half h_buf[2][HID];   // 512 B total

    // W rows {hid + 128r}, K-slice [kq*32, kq*32+32) -> fp16 h2 x16 per row
    h2_t wr[4][16];
#pragma unroll
    for (int r = 0; r < 4; ++r) {
        const float4* Wp = (const float4*)(W + (long)(hid + 128 * r) * 128 + kq * 32);
#pragma unroll
        for (int q = 0; q < 8; ++q) {
            float4 v = Wp[q];
            wr[r][2 * q]     = h2_t{ (_Float16)v.x, (_Float16)v.y };
            wr[r][2 * q + 1] = h2_t{ (_Float16)v.z, (_Float16)v.w };
        }
    }

    if (t < HID) h_buf[0][t] = __float2half(0.f);
    __syncthreads();

    // xg column this lane activates: hid + kq*128
    const __half* xgp = xg + (long)bidx * G4 + hid + kq * 128;
    const long step_stride = (long)BATCH * G4;   // 65536

    float p0 = __half2float(xgp[0]);
    float p1 = __half2float(xgp[step_stride]);

    float c = 0.f, hlast = 0.f;
    const float ascale = (kq == 2) ? 2.f : 1.f;   // tanh = 2*sig(2x)-1 for g
    float* out_h = out + (long)bidx * HID;
    const long SBH = (long)S_LEN * BATCH * HID;

    for (int s = 0; s < S_LEN; ++s) {
        long soff = (long)((s + 2 < S_LEN) ? s + 2 : S_LEN - 1) * step_stride;
        float nx = __half2float(xgp[soff]);
        float xv = p0;

        // read own K-quarter of h (4 x ds_read_b128, 2-way bank alias = free)
        const float4* hp = (const float4*)(&h_buf[s & 1][0]);
        float acc0 = 0.f, acc1 = 0.f, acc2 = 0.f, acc3 = 0.f;
#pragma unroll
        for (int q = 0; q < 4; ++q) {
            union { float4 f; h2_t h[4]; } u;
            u.f = hp[kq * 4 + q];
#pragma unroll
            for (int j = 0; j < 4; ++j) {
                h2_t hh = u.h[j];
                int cidx = q * 4 + j;
                acc0 = FDOT2(wr[0][cidx], hh, acc0);
                acc1 = FDOT2(wr[1][cidx], hh, acc1);
                acc2 = FDOT2(wr[2][cidx], hh, acc2);
                acc3 = FDOT2(wr[3][cidx], hh, acc3);
            }
        }
        // DPP butterfly across the quad: full K-sum in every lane, all 4 rows
        acc0 += dpp_mov_f<QP_XOR1>(acc0);  acc0 += dpp_mov_f<QP_XOR2>(acc0);
        acc1 += dpp_mov_f<QP_XOR1>(acc1);  acc1 += dpp_mov_f<QP_XOR2>(acc1);
        acc2 += dpp_mov_f<QP_XOR1>(acc2);  acc2 += dpp_mov_f<QP_XOR2>(acc2);
        acc3 += dpp_mov_f<QP_XOR1>(acc3);  acc3 += dpp_mov_f<QP_XOR2>(acc3);

        // lane kq activates gate kq (i/f/o sigmoid, g via 2*sig(2x)-1)
        float mydot = acc0;
        mydot = (kq == 1) ? acc1 : mydot;
        mydot = (kq == 2) ? acc2 : mydot;
        mydot = (kq == 3) ? acc3 : mydot;
        float pre = mydot + xv;
        float act = ascale * fsig(ascale * pre) - (ascale - 1.f);

        // quad broadcast: every lane gets i,f,g,o
        float gi = dpp_mov_f<QP_BC0>(act);
        float gf = dpp_mov_f<QP_BC1>(act);
        float gg = dpp_mov_f<QP_BC2>(act);
        float go = dpp_mov_f<QP_BC3>(act);

        c = gf * c + gi * gg;                // redundant x4 per quad, identical
        float h = go * ftanh(c);
        hlast = h;

        if (kq == 0) {
            h_buf[(s + 1) & 1][hid] = __float2half(h);
            out_h[(long)s * (BATCH * HID) + hid] = h;   // stays in flight
        }
        bar();   // lgkmcnt-only: h visible, globals keep flowing

        p0 = p1; p1 = nx;
    }

    if (kq == 0) {
        out[SBH + (long)bidx * HID + hid]                     = hlast;  // h_T
        out[SBH + (long)BATCH * HID + (long)bidx * HID + hid] = c;      // c_T
    }
}

// ---------------------------------------------------------------------------
extern "C" void kernel_launch(void* const* d_in, const int* in_sizes, int n_in,
                              void* d_out, int out_size, void* d_ws, size_t ws_size,
                              hipStream_t stream) {
    const float* x  = (const float*)d_in[0];
    const float* V  = (const float*)d_in[1];
    const float* W  = (const float*)d_in[2];
    const float* b  = (const float*)d_in[3];
    const float* b2 = (const float*)d_in[4];
    float* out = (float*)d_out;
    __half* xg = (__half*)d_ws;   // 2048*128*512*2 = 268435456 B

    dim3 g1(G4 / 128, (S_LEN * BATCH) / 128);   // (4, 2048)
    xg_gemm<<<g1, dim3(256), 0, stream>>>(x, V, b, b2, xg);
    lstm_scan<<<dim3(BATCH), dim3(512), 0, stream>>>(xg, W, out);
}